// Round 16
// baseline (38.682 us; speedup 1.0000x reference)
//
#include <hip/hip_runtime.h>
#include <hip/hip_bf16.h>

typedef __attribute__((ext_vector_type(8))) short bf16x8;
typedef __attribute__((ext_vector_type(4))) float f32x4;

#define B_NUM 2048
#define F_NUM 40
#define E_DIM 32
#define P_NUM 780
#define D_DIM 16
#define PC_N  130           // pair chunks
#define PC_SZ 6             // 130*6 = 780 exactly
#define LN_EPS 1e-3f

// workspace layout (bytes)
#define WF_OFF 0
#define WF_BYTES (P_NUM * 2 * 64 * 8 * 2)          // 1.6 MB W fragments
#define XB_OFF  WF_BYTES
#define XB_BYTES (F_NUM * 4 * B_NUM * 8 * 2)       // 5.2 MB packed bf16 x [f][e8][b][8]
#define DW_OFF  (XB_OFF + XB_BYTES)
#define DW_BYTES 32768                             // bf16 dense_w
#define HP_OFF  (DW_OFF + DW_BYTES)                // hpart 130*2048*16*4 = 17 MB

static __device__ __forceinline__ unsigned short f2b(float f) {
  unsigned u = __builtin_bit_cast(unsigned, f);
  u += 0x7fffu + ((u >> 16) & 1u);                 // round-to-nearest-even
  return (unsigned short)(u >> 16);
}
static __device__ __forceinline__ short f2bs(float f) { return (short)f2b(f); }
static __device__ __forceinline__ short fcvt(float f) {
  return (short)__bfloat16_as_ushort(__float2bfloat16(f));
}
static __device__ __forceinline__ float b2f(unsigned short u) {
  return __builtin_bit_cast(float, (unsigned)u << 16);
}

// ---------------------------------------------------------------------------
// Prep (identical to the proven R9/R15 kernel):
//  blocks [0,640): x -> packed bf16 [f][e8][b][8] (b-minor: coalesced writes).
//  blocks [640,835): W -> per-lane A-fragments, f-permuted rows
//    (m -> fo=(m>>2)*8+frag*4+(m&3)), via LDS transpose. One pair per wave.
//  block 835: dense_w -> bf16 table.
__global__ __launch_bounds__(256) void prep_kernel(
    const float* __restrict__ x, const float* __restrict__ W,
    const float* __restrict__ dw, short* __restrict__ xbp,
    short* __restrict__ wfrag, unsigned short* __restrict__ dwbf) {
  const int lane = threadIdx.x & 63;
  const int wv   = threadIdx.x >> 6;
  const int lhi = lane >> 4, llo = lane & 15;
  __shared__ float wst[4][E_DIM * E_DIM];          // 16 KB, one W_p per wave

  if (blockIdx.x < 640) {
    const int u  = blockIdx.x * 256 + threadIdx.x;
    const int b  = u & (B_NUM - 1);
    const int fp = u >> 11;                        // 0..79: (f, e16-half)
    const int f  = fp >> 1;
    const float* src = x + ((size_t)b * F_NUM + f) * E_DIM + (fp & 1) * 16;
    const float4 v0 = *reinterpret_cast<const float4*>(src);
    const float4 v1 = *reinterpret_cast<const float4*>(src + 4);
    const float4 v2 = *reinterpret_cast<const float4*>(src + 8);
    const float4 v3 = *reinterpret_cast<const float4*>(src + 12);
    const int plane = f * 4 + (fp & 1) * 2;        // e8 plane index
    bf16x8 o0, o1;
    o0[0] = f2bs(v0.x); o0[1] = f2bs(v0.y); o0[2] = f2bs(v0.z); o0[3] = f2bs(v0.w);
    o0[4] = f2bs(v1.x); o0[5] = f2bs(v1.y); o0[6] = f2bs(v1.z); o0[7] = f2bs(v1.w);
    o1[0] = f2bs(v2.x); o1[1] = f2bs(v2.y); o1[2] = f2bs(v2.z); o1[3] = f2bs(v2.w);
    o1[4] = f2bs(v3.x); o1[5] = f2bs(v3.y); o1[6] = f2bs(v3.z); o1[7] = f2bs(v3.w);
    *reinterpret_cast<bf16x8*>(xbp + ((size_t)plane * B_NUM + b) * 8)       = o0;
    *reinterpret_cast<bf16x8*>(xbp + ((size_t)(plane + 1) * B_NUM + b) * 8) = o1;
  } else if (blockIdx.x < 640 + 195) {
    const int p = (blockIdx.x - 640) * 4 + wv;
    const float* Wp = W + (size_t)p * (E_DIM * E_DIM);
#pragma unroll
    for (int k = 0; k < 4; ++k) {
      float4 v = *reinterpret_cast<const float4*>(Wp + k * 256 + lane * 4);
      *reinterpret_cast<float4*>(&wst[wv][k * 256 + lane * 4]) = v;
    }
    // same-wave LDS RAW: compiler inserts lgkmcnt wait; no barrier needed
#pragma unroll
    for (int frag = 0; frag < 2; ++frag) {
      const int fo = (llo >> 2) * 8 + frag * 4 + (llo & 3);   // permuted f
      bf16x8 v;
#pragma unroll
      for (int t = 0; t < 8; ++t)
        v[t] = f2bs(wst[wv][(lhi * 8 + t) * E_DIM + fo]);     // A[m][k]=W[e=k][fo]
      *reinterpret_cast<bf16x8*>(wfrag + ((size_t)(p * 2 + frag) * 64 + lane) * 8) = v;
    }
  } else {
    for (int t = threadIdx.x; t < P_NUM * D_DIM; t += 256) dwbf[t] = f2b(dw[t]);
  }
}

// ---------------------------------------------------------------------------
// Fused dual-MFMA, 4 n-tiles per wave (64 batches), PC_SZ=6 chunks so the
// grid reaches 1040 blocks = 4 blocks/CU (fills launch_bounds residency).
// MFMA1: t[fo,b] = W_p^T xi ; u = bf16(t * xj) is the B-fragment of MFMA2
// whose A = dw[p,d] replicated over k: MFMA2 does the f-reduction AND the
// dense fold, accumulating h[d,b] in one f32x4 per n-tile.
// grid (8, 130) = 1040 blocks, block 256 = 4 waves.
__global__ __launch_bounds__(256, 4) void fused_bilinear_dense_kernel(
    const short* __restrict__ xbp, const short* __restrict__ wfrag,
    const unsigned short* __restrict__ dwbf, float* __restrict__ hpart) {
  const int lane = threadIdx.x & 63;
  const int wv   = threadIdx.x >> 6;
  const int lhi = lane >> 4, llo = lane & 15;
  const int bb = blockIdx.x * 256 + wv * 64;
  const int pc = blockIdx.y;
  const int p0 = pc * PC_SZ;

  int off[4];                                      // packed-table lane offsets
#pragma unroll
  for (int nt = 0; nt < 4; ++nt)
    off[nt] = (lhi * B_NUM + bb + nt * 16 + llo) * 8;
#define XB8(f, o) (*reinterpret_cast<const bf16x8*>(xbp + (size_t)(f) * 65536 + (o)))
#define AFR(p, fr) (*reinterpret_cast<const bf16x8*>( \
    wfrag + ((size_t)((p) * 2 + (fr)) * 64 + lane) * 8))

  // pair walk (combinations(range(40),2) order)
  int ii[PC_SZ], jj[PC_SZ];
  {
    int i = 0;
    while ((i + 1) * (79 - (i + 1)) / 2 <= p0) ++i;
    ii[0] = i; jj[0] = i + 1 + (p0 - i * (79 - i) / 2);
  }
#pragma unroll
  for (int k = 1; k < PC_SZ; ++k) {
    int in_ = ii[k - 1], jn = jj[k - 1] + 1;
    if (jn == F_NUM) { ++in_; jn = in_ + 1; }
    ii[k] = in_; jj[k] = jn;
  }

  bf16x8 bf[4], xj[4];
#pragma unroll
  for (int nt = 0; nt < 4; ++nt) {
    bf[nt] = XB8(ii[0], off[nt]);
    xj[nt] = XB8(jj[0], off[nt]);
  }
  bf16x8 a0 = AFR(p0, 0), a1 = AFR(p0, 1);
  unsigned short dwb = dwbf[p0 * D_DIM + llo];

  f32x4 acc[4];
#pragma unroll
  for (int nt = 0; nt < 4; ++nt) acc[nt] = {0.f, 0.f, 0.f, 0.f};
  const f32x4 z = {0.f, 0.f, 0.f, 0.f};

#pragma unroll
  for (int k = 0; k < PC_SZ; ++k) {
    // ---- 1-deep prefetch of pair k+1 (xj / a-frags / dw only) ----
    bf16x8 nxj[4];
    bf16x8 na0 = a0, na1 = a1;
    unsigned short ndw = dwb;
#pragma unroll
    for (int nt = 0; nt < 4; ++nt) nxj[nt] = xj[nt];
    if (k + 1 < PC_SZ) {
#pragma unroll
      for (int nt = 0; nt < 4; ++nt) nxj[nt] = XB8(jj[k + 1], off[nt]);
      na0 = AFR(p0 + k + 1, 0);
      na1 = AFR(p0 + k + 1, 1);
      ndw = dwbf[(p0 + k + 1) * D_DIM + llo];
    }

    // ---- compute pair k: 8 MFMA1 sharing a0/a1 across 4 B-frags ----
    f32x4 c0[4], c1[4];
#pragma unroll
    for (int nt = 0; nt < 4; ++nt) {
      c0[nt] = __builtin_amdgcn_mfma_f32_16x16x32_bf16(a0, bf[nt], z, 0, 0, 0);
      c1[nt] = __builtin_amdgcn_mfma_f32_16x16x32_bf16(a1, bf[nt], z, 0, 0, 0);
    }

    bf16x8 a2;
#pragma unroll
    for (int t = 0; t < 8; ++t) a2[t] = (short)dwb;

#pragma unroll
    for (int nt = 0; nt < 4; ++nt) {
      bf16x8 u;                                    // B-frag of MFMA2
#pragma unroll
      for (int t = 0; t < 4; ++t) {
        u[t]     = fcvt(c0[nt][t] * b2f((unsigned short)xj[nt][t]));
        u[t + 4] = fcvt(c1[nt][t] * b2f((unsigned short)xj[nt][t + 4]));
      }
      acc[nt] = __builtin_amdgcn_mfma_f32_16x16x32_bf16(a2, u, acc[nt], 0, 0, 0);
    }

    // ---- rotate; xi reload only on (rare) i-change, not prefetched ----
#pragma unroll
    for (int nt = 0; nt < 4; ++nt) xj[nt] = nxj[nt];
    a0 = na0; a1 = na1; dwb = ndw;
    if (k + 1 < PC_SZ && ii[k + 1] != ii[k]) {     // wave-uniform branch
#pragma unroll
      for (int nt = 0; nt < 4; ++nt) bf[nt] = XB8(ii[k + 1], off[nt]);
    }
  }
#undef XB8
#undef AFR

  // C2 layout: lane holds b=llo, d=lhi*4+r -> coalesced float4 stores
  float* hp = hpart + (size_t)pc * B_NUM * D_DIM;
#pragma unroll
  for (int nt = 0; nt < 4; ++nt)
    *reinterpret_cast<f32x4*>(hp + (size_t)(bb + nt * 16 + llo) * D_DIM + lhi * 4) = acc[nt];
}

// ---------------------------------------------------------------------------
// Final: sum 130 h-partials + bias, LayerNorm. grid 128, block 256;
// thread = (b, d): per-pc the block reads 1 KB contiguous.
__global__ __launch_bounds__(256) void reduce_ln_kernel(
    const float* __restrict__ hpart, const float* __restrict__ bias,
    const float* __restrict__ gamma, const float* __restrict__ beta,
    float* __restrict__ out) {
  const int t = threadIdx.x;
  const int d = t & 15;
  const int b = blockIdx.x * 16 + (t >> 4);
  float acc = bias[d];
  const float* hp = hpart + (size_t)b * D_DIM + d;
#pragma unroll 5
  for (int pc = 0; pc < PC_N; ++pc)
    acc += hp[(size_t)pc * B_NUM * D_DIM];

  float sum = acc;
  sum += __shfl_xor(sum, 1); sum += __shfl_xor(sum, 2);
  sum += __shfl_xor(sum, 4); sum += __shfl_xor(sum, 8);
  const float mu = sum * (1.f / D_DIM);
  const float dev = acc - mu;
  float v = dev * dev;
  v += __shfl_xor(v, 1); v += __shfl_xor(v, 2);
  v += __shfl_xor(v, 4); v += __shfl_xor(v, 8);
  const float rs = rsqrtf(v * (1.f / D_DIM) + LN_EPS);
  out[(size_t)b * D_DIM + d] = dev * rs * gamma[d] + beta[d];
}

extern "C" void kernel_launch(void* const* d_in, const int* in_sizes, int n_in,
                              void* d_out, int out_size, void* d_ws, size_t ws_size,
                              hipStream_t stream) {
  const float* x     = (const float*)d_in[0];
  const float* W     = (const float*)d_in[1];
  const float* dw    = (const float*)d_in[2];
  const float* db    = (const float*)d_in[3];
  const float* gamma = (const float*)d_in[4];
  const float* beta  = (const float*)d_in[5];
  float* out = (float*)d_out;

  short*          wfrag = (short*)((char*)d_ws + WF_OFF);
  short*          xbp   = (short*)((char*)d_ws + XB_OFF);
  unsigned short* dwbf  = (unsigned short*)((char*)d_ws + DW_OFF);
  float*          hpart = (float*)((char*)d_ws + HP_OFF);

  prep_kernel<<<640 + 195 + 1, 256, 0, stream>>>(x, W, dw, xbp, wfrag, dwbf);

  dim3 gA(B_NUM / 256, PC_N);
  fused_bilinear_dense_kernel<<<gA, 256, 0, stream>>>(xbp, wfrag, dwbf, hpart);

  reduce_ln_kernel<<<B_NUM / 16, 256, 0, stream>>>(hpart, db, gamma, beta, out);
}

// Round 17
// 34.150 us; speedup vs baseline: 1.1327x; 1.1327x over previous
//
#include <hip/hip_runtime.h>
#include <hip/hip_bf16.h>

typedef __attribute__((ext_vector_type(8))) short bf16x8;
typedef __attribute__((ext_vector_type(4))) float f32x4;

#define B_NUM 2048
#define F_NUM 40
#define E_DIM 32
#define P_NUM 780
#define D_DIM 16
#define PC_N  65            // pair chunks
#define PC_SZ 12            // 65*12 = 780 exactly
#define LN_EPS 1e-3f

// workspace layout (bytes)
#define WF_OFF 0
#define WF_BYTES (P_NUM * 2 * 64 * 8 * 2)          // 1.6 MB W fragments
#define XB_OFF  WF_BYTES
#define XB_BYTES (F_NUM * 4 * B_NUM * 8 * 2)       // 5.2 MB packed bf16 x [f][e8][b][8]
#define DW_OFF  (XB_OFF + XB_BYTES)
#define DW_BYTES 32768                             // bf16 dense_w
#define HP_OFF  (DW_OFF + DW_BYTES)                // hpart 65*2048*16*4 = 8.5 MB

static __device__ __forceinline__ unsigned short f2b(float f) {
  unsigned u = __builtin_bit_cast(unsigned, f);
  u += 0x7fffu + ((u >> 16) & 1u);                 // round-to-nearest-even
  return (unsigned short)(u >> 16);
}
static __device__ __forceinline__ short f2bs(float f) { return (short)f2b(f); }
static __device__ __forceinline__ short fcvt(float f) {
  return (short)__bfloat16_as_ushort(__float2bfloat16(f));
}
static __device__ __forceinline__ float b2f(unsigned short u) {
  return __builtin_bit_cast(float, (unsigned)u << 16);
}

// ---------------------------------------------------------------------------
// Prep (identical to the proven R9/R15 kernel):
//  blocks [0,640): x -> packed bf16 [f][e8][b][8] (b-minor: coalesced writes).
//  blocks [640,835): W -> per-lane A-fragments, f-permuted rows
//    (m -> fo=(m>>2)*8+frag*4+(m&3)), via LDS transpose. One pair per wave.
//  block 835: dense_w -> bf16 table.
__global__ __launch_bounds__(256) void prep_kernel(
    const float* __restrict__ x, const float* __restrict__ W,
    const float* __restrict__ dw, short* __restrict__ xbp,
    short* __restrict__ wfrag, unsigned short* __restrict__ dwbf) {
  const int lane = threadIdx.x & 63;
  const int wv   = threadIdx.x >> 6;
  const int lhi = lane >> 4, llo = lane & 15;
  __shared__ float wst[4][E_DIM * E_DIM];          // 16 KB, one W_p per wave

  if (blockIdx.x < 640) {
    const int u  = blockIdx.x * 256 + threadIdx.x;
    const int b  = u & (B_NUM - 1);
    const int fp = u >> 11;                        // 0..79: (f, e16-half)
    const int f  = fp >> 1;
    const float* src = x + ((size_t)b * F_NUM + f) * E_DIM + (fp & 1) * 16;
    const float4 v0 = *reinterpret_cast<const float4*>(src);
    const float4 v1 = *reinterpret_cast<const float4*>(src + 4);
    const float4 v2 = *reinterpret_cast<const float4*>(src + 8);
    const float4 v3 = *reinterpret_cast<const float4*>(src + 12);
    const int plane = f * 4 + (fp & 1) * 2;        // e8 plane index
    bf16x8 o0, o1;
    o0[0] = f2bs(v0.x); o0[1] = f2bs(v0.y); o0[2] = f2bs(v0.z); o0[3] = f2bs(v0.w);
    o0[4] = f2bs(v1.x); o0[5] = f2bs(v1.y); o0[6] = f2bs(v1.z); o0[7] = f2bs(v1.w);
    o1[0] = f2bs(v2.x); o1[1] = f2bs(v2.y); o1[2] = f2bs(v2.z); o1[3] = f2bs(v2.w);
    o1[4] = f2bs(v3.x); o1[5] = f2bs(v3.y); o1[6] = f2bs(v3.z); o1[7] = f2bs(v3.w);
    *reinterpret_cast<bf16x8*>(xbp + ((size_t)plane * B_NUM + b) * 8)       = o0;
    *reinterpret_cast<bf16x8*>(xbp + ((size_t)(plane + 1) * B_NUM + b) * 8) = o1;
  } else if (blockIdx.x < 640 + 195) {
    const int p = (blockIdx.x - 640) * 4 + wv;
    const float* Wp = W + (size_t)p * (E_DIM * E_DIM);
#pragma unroll
    for (int k = 0; k < 4; ++k) {
      float4 v = *reinterpret_cast<const float4*>(Wp + k * 256 + lane * 4);
      *reinterpret_cast<float4*>(&wst[wv][k * 256 + lane * 4]) = v;
    }
    // same-wave LDS RAW: compiler inserts lgkmcnt wait; no barrier needed
#pragma unroll
    for (int frag = 0; frag < 2; ++frag) {
      const int fo = (llo >> 2) * 8 + frag * 4 + (llo & 3);   // permuted f
      bf16x8 v;
#pragma unroll
      for (int t = 0; t < 8; ++t)
        v[t] = f2bs(wst[wv][(lhi * 8 + t) * E_DIM + fo]);     // A[m][k]=W[e=k][fo]
      *reinterpret_cast<bf16x8*>(wfrag + ((size_t)(p * 2 + frag) * 64 + lane) * 8) = v;
    }
  } else {
    for (int t = threadIdx.x; t < P_NUM * D_DIM; t += 256) dwbf[t] = f2b(dw[t]);
  }
}

// ---------------------------------------------------------------------------
// Fused dual-MFMA, 4 n-tiles per wave (64 batches), 2-deep register pipeline.
// launch_bounds (256,2): the grid provides only 2 blocks/CU, so cap VGPR at
// 256 (not 128) and let ALL prologue/prefetch loads stay in flight.
// MFMA1: t[fo,b] = W_p^T xi ; u = bf16(t * xj) is the B-fragment of MFMA2
// whose A = dw[p,d] replicated over k: MFMA2 does the f-reduction AND the
// dense fold, accumulating h[d,b] in one f32x4 per n-tile.
// grid (8, 65) = 520 blocks, block 256 = 4 waves.
__global__ __launch_bounds__(256, 2) void fused_bilinear_dense_kernel(
    const short* __restrict__ xbp, const short* __restrict__ wfrag,
    const unsigned short* __restrict__ dwbf, float* __restrict__ hpart) {
  const int lane = threadIdx.x & 63;
  const int wv   = threadIdx.x >> 6;
  const int lhi = lane >> 4, llo = lane & 15;
  const int bb = blockIdx.x * 256 + wv * 64;
  const int pc = blockIdx.y;
  const int p0 = pc * PC_SZ;

  int off[4];                                      // packed-table lane offsets
#pragma unroll
  for (int nt = 0; nt < 4; ++nt)
    off[nt] = (lhi * B_NUM + bb + nt * 16 + llo) * 8;
#define XB8(f, o) (*reinterpret_cast<const bf16x8*>(xbp + (size_t)(f) * 65536 + (o)))
#define AFR(p, fr) (*reinterpret_cast<const bf16x8*>( \
    wfrag + ((size_t)((p) * 2 + (fr)) * 64 + lane) * 8))

  // pair walk (combinations(range(40),2) order)
  int ii[PC_SZ], jj[PC_SZ];
  {
    int i = 0;
    while ((i + 1) * (79 - (i + 1)) / 2 <= p0) ++i;
    ii[0] = i; jj[0] = i + 1 + (p0 - i * (79 - i) / 2);
  }
#pragma unroll
  for (int k = 1; k < PC_SZ; ++k) {
    int in_ = ii[k - 1], jn = jj[k - 1] + 1;
    if (jn == F_NUM) { ++in_; jn = in_ + 1; }
    ii[k] = in_; jj[k] = jn;
  }

  // xi fragments (reloaded on rare i-change only)
  bf16x8 bf[4];
#pragma unroll
  for (int nt = 0; nt < 4; ++nt) bf[nt] = XB8(ii[0], off[nt]);

  // 2-deep stages (slot = k&1; static under full unroll -> registers)
  bf16x8 sxj[2][4], sa0[2], sa1[2];
  unsigned short sdw[2];
#pragma unroll
  for (int s = 0; s < 2; ++s) {
#pragma unroll
    for (int nt = 0; nt < 4; ++nt) sxj[s][nt] = XB8(jj[s], off[nt]);
    sa0[s] = AFR(p0 + s, 0);
    sa1[s] = AFR(p0 + s, 1);
    sdw[s] = dwbf[(p0 + s) * D_DIM + llo];
  }

  f32x4 acc[4];
#pragma unroll
  for (int nt = 0; nt < 4; ++nt) acc[nt] = {0.f, 0.f, 0.f, 0.f};
  const f32x4 z = {0.f, 0.f, 0.f, 0.f};

#pragma unroll
  for (int k = 0; k < PC_SZ; ++k) {
    const int s = k & 1;
    // consume stage s into locals
    const bf16x8 a0 = sa0[s], a1 = sa1[s];
    const bf16x8 xj0 = sxj[s][0], xj1 = sxj[s][1];
    const bf16x8 xj2 = sxj[s][2], xj3 = sxj[s][3];
    const unsigned short dwb = sdw[s];
    // refill stage s with pair k+2 (lands while k and k+1 compute)
    if (k + 2 < PC_SZ) {
#pragma unroll
      for (int nt = 0; nt < 4; ++nt) sxj[s][nt] = XB8(jj[k + 2], off[nt]);
      sa0[s] = AFR(p0 + k + 2, 0);
      sa1[s] = AFR(p0 + k + 2, 1);
      sdw[s] = dwbf[(p0 + k + 2) * D_DIM + llo];
    }

    // ---- compute pair k: MFMA + u-pack cluster under raised priority ----
    __builtin_amdgcn_s_setprio(1);
    f32x4 c0[4], c1[4];
#pragma unroll
    for (int nt = 0; nt < 4; ++nt) {
      c0[nt] = __builtin_amdgcn_mfma_f32_16x16x32_bf16(a0, bf[nt], z, 0, 0, 0);
      c1[nt] = __builtin_amdgcn_mfma_f32_16x16x32_bf16(a1, bf[nt], z, 0, 0, 0);
    }

    bf16x8 a2;
#pragma unroll
    for (int t = 0; t < 8; ++t) a2[t] = (short)dwb;

    const bf16x8 xjl[4] = {xj0, xj1, xj2, xj3};
#pragma unroll
    for (int nt = 0; nt < 4; ++nt) {
      bf16x8 u;                                    // B-frag of MFMA2
#pragma unroll
      for (int t = 0; t < 4; ++t) {
        u[t]     = fcvt(c0[nt][t] * b2f((unsigned short)xjl[nt][t]));
        u[t + 4] = fcvt(c1[nt][t] * b2f((unsigned short)xjl[nt][t + 4]));
      }
      acc[nt] = __builtin_amdgcn_mfma_f32_16x16x32_bf16(a2, u, acc[nt], 0, 0, 0);
    }
    __builtin_amdgcn_s_setprio(0);

    // xi reload on (rare) i-change, wave-uniform branch
    if (k + 1 < PC_SZ && ii[k + 1] != ii[k]) {
#pragma unroll
      for (int nt = 0; nt < 4; ++nt) bf[nt] = XB8(ii[k + 1], off[nt]);
    }
  }
#undef XB8
#undef AFR

  // C2 layout: lane holds b=llo, d=lhi*4+r -> coalesced float4 stores
  float* hp = hpart + (size_t)pc * B_NUM * D_DIM;
#pragma unroll
  for (int nt = 0; nt < 4; ++nt)
    *reinterpret_cast<f32x4*>(hp + (size_t)(bb + nt * 16 + llo) * D_DIM + lhi * 4) = acc[nt];
}

// ---------------------------------------------------------------------------
// Final: sum 65 h-partials + bias, LayerNorm. grid 128, block 256;
// thread = (b, d): per-pc the block reads 1 KB contiguous.
__global__ __launch_bounds__(256) void reduce_ln_kernel(
    const float* __restrict__ hpart, const float* __restrict__ bias,
    const float* __restrict__ gamma, const float* __restrict__ beta,
    float* __restrict__ out) {
  const int t = threadIdx.x;
  const int d = t & 15;
  const int b = blockIdx.x * 16 + (t >> 4);
  float acc = bias[d];
  const float* hp = hpart + (size_t)b * D_DIM + d;
#pragma unroll 5
  for (int pc = 0; pc < PC_N; ++pc)
    acc += hp[(size_t)pc * B_NUM * D_DIM];

  float sum = acc;
  sum += __shfl_xor(sum, 1); sum += __shfl_xor(sum, 2);
  sum += __shfl_xor(sum, 4); sum += __shfl_xor(sum, 8);
  const float mu = sum * (1.f / D_DIM);
  const float dev = acc - mu;
  float v = dev * dev;
  v += __shfl_xor(v, 1); v += __shfl_xor(v, 2);
  v += __shfl_xor(v, 4); v += __shfl_xor(v, 8);
  const float rs = rsqrtf(v * (1.f / D_DIM) + LN_EPS);
  out[(size_t)b * D_DIM + d] = dev * rs * gamma[d] + beta[d];
}

extern "C" void kernel_launch(void* const* d_in, const int* in_sizes, int n_in,
                              void* d_out, int out_size, void* d_ws, size_t ws_size,
                              hipStream_t stream) {
  const float* x     = (const float*)d_in[0];
  const float* W     = (const float*)d_in[1];
  const float* dw    = (const float*)d_in[2];
  const float* db    = (const float*)d_in[3];
  const float* gamma = (const float*)d_in[4];
  const float* beta  = (const float*)d_in[5];
  float* out = (float*)d_out;

  short*          wfrag = (short*)((char*)d_ws + WF_OFF);
  short*          xbp   = (short*)((char*)d_ws + XB_OFF);
  unsigned short* dwbf  = (unsigned short*)((char*)d_ws + DW_OFF);
  float*          hpart = (float*)((char*)d_ws + HP_OFF);

  prep_kernel<<<640 + 195 + 1, 256, 0, stream>>>(x, W, dw, xbp, wfrag, dwbf);

  dim3 gA(B_NUM / 256, PC_N);
  fused_bilinear_dense_kernel<<<gA, 256, 0, stream>>>(xbp, wfrag, dwbf, hpart);

  reduce_ln_kernel<<<B_NUM / 16, 256, 0, stream>>>(hpart, db, gamma, beta, out);
}

// Round 18
// 30.912 us; speedup vs baseline: 1.2514x; 1.1048x over previous
//
#include <hip/hip_runtime.h>
#include <hip/hip_bf16.h>

typedef __attribute__((ext_vector_type(8))) short bf16x8;
typedef __attribute__((ext_vector_type(4))) float f32x4;
typedef __attribute__((ext_vector_type(4))) unsigned short u16x4;

#define B_NUM 2048
#define F_NUM 40
#define E_DIM 32
#define P_NUM 780
#define D_DIM 16
#define PC_N  65            // pair chunks
#define PC_SZ 12            // 65*12 = 780 exactly
#define LN_EPS 1e-3f

// workspace layout (bytes)
#define XB_OFF  0
#define XB_BYTES (F_NUM * 4 * B_NUM * 8 * 2)       // 5.2 MB packed bf16 x [f][e8][b][8]
#define HP_OFF  XB_BYTES                           // hpart 65*2048*16*4 = 8.5 MB

static __device__ __forceinline__ unsigned short f2b(float f) {
  unsigned u = __builtin_bit_cast(unsigned, f);
  u += 0x7fffu + ((u >> 16) & 1u);                 // round-to-nearest-even
  return (unsigned short)(u >> 16);
}
static __device__ __forceinline__ short f2bs(float f) { return (short)f2b(f); }
static __device__ __forceinline__ short fcvt(float f) {
  return (short)__bfloat16_as_ushort(__float2bfloat16(f));
}
static __device__ __forceinline__ float b2f(unsigned short u) {
  return __builtin_bit_cast(float, (unsigned)u << 16);
}

// ---------------------------------------------------------------------------
// Prep (x-pack ONLY; W/dw prep moved into the fused kernel):
// x -> packed bf16 [f][e8][b][8], b-minor: reads one full 64 B half-row per
// thread (100% line use), writes two coalesced 16 B planes. 640 blocks.
__global__ __launch_bounds__(256) void xpack_kernel(
    const float* __restrict__ x, short* __restrict__ xbp) {
  const int u  = blockIdx.x * 256 + threadIdx.x;
  const int b  = u & (B_NUM - 1);
  const int fp = u >> 11;                          // 0..79: (f, e16-half)
  const int f  = fp >> 1;
  const float* src = x + ((size_t)b * F_NUM + f) * E_DIM + (fp & 1) * 16;
  const float4 v0 = *reinterpret_cast<const float4*>(src);
  const float4 v1 = *reinterpret_cast<const float4*>(src + 4);
  const float4 v2 = *reinterpret_cast<const float4*>(src + 8);
  const float4 v3 = *reinterpret_cast<const float4*>(src + 12);
  const int plane = f * 4 + (fp & 1) * 2;          // e8 plane index
  bf16x8 o0, o1;
  o0[0] = f2bs(v0.x); o0[1] = f2bs(v0.y); o0[2] = f2bs(v0.z); o0[3] = f2bs(v0.w);
  o0[4] = f2bs(v1.x); o0[5] = f2bs(v1.y); o0[6] = f2bs(v1.z); o0[7] = f2bs(v1.w);
  o1[0] = f2bs(v2.x); o1[1] = f2bs(v2.y); o1[2] = f2bs(v2.z); o1[3] = f2bs(v2.w);
  o1[4] = f2bs(v3.x); o1[5] = f2bs(v3.y); o1[6] = f2bs(v3.z); o1[7] = f2bs(v3.w);
  *reinterpret_cast<bf16x8*>(xbp + ((size_t)plane * B_NUM + b) * 8)       = o0;
  *reinterpret_cast<bf16x8*>(xbp + ((size_t)(plane + 1) * B_NUM + b) * 8) = o1;
}

// ---------------------------------------------------------------------------
// Fused dual-MFMA; W-fragments built in-LDS per block (R13-proven technique,
// combined for the first time with the packed-x reads of R15/R17).
//   MFMA1: t[fo,b] = W_p^T xi ; u = bf16(t * xj) is the B-fragment of MFMA2
//   whose A = dw[p,d] replicated over k: MFMA2 does the f-reduction AND the
//   dense fold, accumulating h[d,b] in one f32x4 per n-tile (64 batches/wave).
// grid (8, 65) = 520 blocks, block 256 = 4 waves; LDS 48 KB -> 2 blocks/CU.
__global__ __launch_bounds__(256, 2) void fused_bilinear_dense_kernel(
    const float* __restrict__ W, const float* __restrict__ dw,
    const short* __restrict__ xbp, float* __restrict__ hpart) {
  __shared__ unsigned short wraw[PC_SZ * 1024];                  // 24 KB bf16 W [pl][e][f]
  __shared__ __align__(16) unsigned short afrag[PC_SZ * 2 * 512];// 24 KB a-frags
  const int tid  = threadIdx.x;
  const int lane = tid & 63, wv = tid >> 6;
  const int lhi = lane >> 4, llo = lane & 15;
  const int bb = blockIdx.x * 256 + wv * 64;
  const int pc = blockIdx.y;
  const int p0 = pc * PC_SZ;

  // ---- stage this chunk's 12 W matrices (48 KB f32 -> 24 KB bf16 LDS) ----
  {
    const float* Wsrc = W + (size_t)p0 * 1024;
#pragma unroll
    for (int it = 0; it < PC_SZ; ++it) {
      const int L = it * 1024 + tid * 4;
      float4 v = *reinterpret_cast<const float4*>(Wsrc + L);
      u16x4 o;
      o[0] = f2b(v.x); o[1] = f2b(v.y); o[2] = f2b(v.z); o[3] = f2b(v.w);
      *reinterpret_cast<u16x4*>(&wraw[L]) = o;                   // ds_write_b64
    }
  }
  __syncthreads();

  // ---- build per-lane A-fragments with f-PERMUTED m-rows ----
  // A-frag (16x16x32): lane l holds A[m=l&15][k=(l>>4)*8+t]; m -> fo =
  // (m>>2)*8+frag*4+(m&3), so C-row m=lhi*4+r maps to fo=lhi*8+frag*4+r.
#pragma unroll
  for (int s = 0; s < 3; ++s) {
    const int pl = wv * 3 + s;
#pragma unroll
    for (int frag = 0; frag < 2; ++frag) {
      const int fo = (llo >> 2) * 8 + frag * 4 + (llo & 3);
      bf16x8 v;
#pragma unroll
      for (int t = 0; t < 8; ++t)
        v[t] = (short)wraw[pl * 1024 + (lhi * 8 + t) * E_DIM + fo];
      *reinterpret_cast<bf16x8*>(&afrag[(pl * 2 + frag) * 512 + lane * 8]) = v;
    }
  }
  __syncthreads();

  int off[4];                                      // packed-table lane offsets
#pragma unroll
  for (int nt = 0; nt < 4; ++nt)
    off[nt] = (lhi * B_NUM + bb + nt * 16 + llo) * 8;
#define XB8(f, o) (*reinterpret_cast<const bf16x8*>(xbp + (size_t)(f) * 65536 + (o)))

  // pair walk (combinations(range(40),2) order)
  int ii[PC_SZ], jj[PC_SZ];
  {
    int i = 0;
    while ((i + 1) * (79 - (i + 1)) / 2 <= p0) ++i;
    ii[0] = i; jj[0] = i + 1 + (p0 - i * (79 - i) / 2);
  }
#pragma unroll
  for (int k = 1; k < PC_SZ; ++k) {
    int in_ = ii[k - 1], jn = jj[k - 1] + 1;
    if (jn == F_NUM) { ++in_; jn = in_ + 1; }
    ii[k] = in_; jj[k] = jn;
  }

  // xi fragments (reloaded on rare i-change only)
  bf16x8 bf[4];
#pragma unroll
  for (int nt = 0; nt < 4; ++nt) bf[nt] = XB8(ii[0], off[nt]);

  // 2-deep stages for global-memory operands (xj, dw); a-frags come from LDS
  bf16x8 sxj[2][4];
  float sdwf[2];
#pragma unroll
  for (int s = 0; s < 2; ++s) {
#pragma unroll
    for (int nt = 0; nt < 4; ++nt) sxj[s][nt] = XB8(jj[s], off[nt]);
    sdwf[s] = dw[(p0 + s) * D_DIM + llo];
  }

  f32x4 acc[4];
#pragma unroll
  for (int nt = 0; nt < 4; ++nt) acc[nt] = {0.f, 0.f, 0.f, 0.f};
  const f32x4 z = {0.f, 0.f, 0.f, 0.f};

#pragma unroll
  for (int k = 0; k < PC_SZ; ++k) {
    const int s = k & 1;
    const bf16x8 xj0 = sxj[s][0], xj1 = sxj[s][1];
    const bf16x8 xj2 = sxj[s][2], xj3 = sxj[s][3];
    const float dwf = sdwf[s];
    // refill stage s with pair k+2 (lands while k and k+1 compute)
    if (k + 2 < PC_SZ) {
#pragma unroll
      for (int nt = 0; nt < 4; ++nt) sxj[s][nt] = XB8(jj[k + 2], off[nt]);
      sdwf[s] = dw[(p0 + k + 2) * D_DIM + llo];
    }

    // a-frags from LDS (ds_read_b128, compiler-inserted lgkmcnt)
    const bf16x8 a0 = *reinterpret_cast<const bf16x8*>(&afrag[(k * 2 + 0) * 512 + lane * 8]);
    const bf16x8 a1 = *reinterpret_cast<const bf16x8*>(&afrag[(k * 2 + 1) * 512 + lane * 8]);

    // ---- compute pair k: MFMA + u-pack cluster under raised priority ----
    __builtin_amdgcn_s_setprio(1);
    f32x4 c0[4], c1[4];
#pragma unroll
    for (int nt = 0; nt < 4; ++nt) {
      c0[nt] = __builtin_amdgcn_mfma_f32_16x16x32_bf16(a0, bf[nt], z, 0, 0, 0);
      c1[nt] = __builtin_amdgcn_mfma_f32_16x16x32_bf16(a1, bf[nt], z, 0, 0, 0);
    }

    const short dwb = fcvt(dwf);
    bf16x8 a2;
#pragma unroll
    for (int t = 0; t < 8; ++t) a2[t] = dwb;

    const bf16x8 xjl[4] = {xj0, xj1, xj2, xj3};
#pragma unroll
    for (int nt = 0; nt < 4; ++nt) {
      bf16x8 u;                                    // B-frag of MFMA2
#pragma unroll
      for (int t = 0; t < 4; ++t) {
        u[t]     = fcvt(c0[nt][t] * b2f((unsigned short)xjl[nt][t]));
        u[t + 4] = fcvt(c1[nt][t] * b2f((unsigned short)xjl[nt][t + 4]));
      }
      acc[nt] = __builtin_amdgcn_mfma_f32_16x16x32_bf16(a2, u, acc[nt], 0, 0, 0);
    }
    __builtin_amdgcn_s_setprio(0);

    // xi reload on (rare) i-change, wave-uniform branch
    if (k + 1 < PC_SZ && ii[k + 1] != ii[k]) {
#pragma unroll
      for (int nt = 0; nt < 4; ++nt) bf[nt] = XB8(ii[k + 1], off[nt]);
    }
  }
#undef XB8

  // C2 layout: lane holds b=llo, d=lhi*4+r -> coalesced float4 stores
  float* hp = hpart + (size_t)pc * B_NUM * D_DIM;
#pragma unroll
  for (int nt = 0; nt < 4; ++nt)
    *reinterpret_cast<f32x4*>(hp + (size_t)(bb + nt * 16 + llo) * D_DIM + lhi * 4) = acc[nt];
}

// ---------------------------------------------------------------------------
// Final: sum 65 h-partials + bias, LayerNorm. grid 128, block 256;
// thread = (b, d): per-pc the block reads 1 KB contiguous; unroll 13 keeps
// 13 independent loads in flight per thread.
__global__ __launch_bounds__(256) void reduce_ln_kernel(
    const float* __restrict__ hpart, const float* __restrict__ bias,
    const float* __restrict__ gamma, const float* __restrict__ beta,
    float* __restrict__ out) {
  const int t = threadIdx.x;
  const int d = t & 15;
  const int b = blockIdx.x * 16 + (t >> 4);
  float acc = bias[d];
  const float* hp = hpart + (size_t)b * D_DIM + d;
#pragma unroll 13
  for (int pc = 0; pc < PC_N; ++pc)
    acc += hp[(size_t)pc * B_NUM * D_DIM];

  float sum = acc;
  sum += __shfl_xor(sum, 1); sum += __shfl_xor(sum, 2);
  sum += __shfl_xor(sum, 4); sum += __shfl_xor(sum, 8);
  const float mu = sum * (1.f / D_DIM);
  const float dev = acc - mu;
  float v = dev * dev;
  v += __shfl_xor(v, 1); v += __shfl_xor(v, 2);
  v += __shfl_xor(v, 4); v += __shfl_xor(v, 8);
  const float rs = rsqrtf(v * (1.f / D_DIM) + LN_EPS);
  out[(size_t)b * D_DIM + d] = dev * rs * gamma[d] + beta[d];
}

extern "C" void kernel_launch(void* const* d_in, const int* in_sizes, int n_in,
                              void* d_out, int out_size, void* d_ws, size_t ws_size,
                              hipStream_t stream) {
  const float* x     = (const float*)d_in[0];
  const float* W     = (const float*)d_in[1];
  const float* dw    = (const float*)d_in[2];
  const float* db    = (const float*)d_in[3];
  const float* gamma = (const float*)d_in[4];
  const float* beta  = (const float*)d_in[5];
  float* out = (float*)d_out;

  short* xbp   = (short*)((char*)d_ws + XB_OFF);
  float* hpart = (float*)((char*)d_ws + HP_OFF);

  xpack_kernel<<<640, 256, 0, stream>>>(x, xbp);

  dim3 gA(B_NUM / 256, PC_N);
  fused_bilinear_dense_kernel<<<gA, 256, 0, stream>>>(W, dw, xbp, hpart);

  reduce_ln_kernel<<<B_NUM / 16, 256, 0, stream>>>(hpart, db, gamma, beta, out);
}

// Round 19
// 29.577 us; speedup vs baseline: 1.3078x; 1.0451x over previous
//
#include <hip/hip_runtime.h>
#include <hip/hip_bf16.h>

typedef __attribute__((ext_vector_type(8))) short bf16x8;
typedef __attribute__((ext_vector_type(4))) float f32x4;
typedef __attribute__((ext_vector_type(4))) unsigned short u16x4;

#define B_NUM 2048
#define F_NUM 40
#define E_DIM 32
#define P_NUM 780
#define D_DIM 16
#define PC_N  65            // pair chunks
#define PC_SZ 12            // 65*12 = 780 exactly
#define LN_EPS 1e-3f

// workspace layout (bytes)
#define XB_OFF  0
#define XB_BYTES (F_NUM * 4 * B_NUM * 8 * 2)       // 5.2 MB packed bf16 x [f][e8][b][8]
#define HP_OFF  XB_BYTES                           // hpart bf16 [PC_N][B][D] = 4.25 MB

static __device__ __forceinline__ unsigned short f2b(float f) {
  unsigned u = __builtin_bit_cast(unsigned, f);
  u += 0x7fffu + ((u >> 16) & 1u);                 // round-to-nearest-even
  return (unsigned short)(u >> 16);
}
static __device__ __forceinline__ short f2bs(float f) { return (short)f2b(f); }
static __device__ __forceinline__ short fcvt(float f) {
  return (short)__bfloat16_as_ushort(__float2bfloat16(f));
}
static __device__ __forceinline__ float b2f(unsigned short u) {
  return __builtin_bit_cast(float, (unsigned)u << 16);
}

// ---------------------------------------------------------------------------
// Prep (x-pack only): x -> packed bf16 [f][e8][b][8], b-minor. Each thread
// reads one 64 B half-row (100% line use), writes two coalesced 16 B planes.
__global__ __launch_bounds__(256) void xpack_kernel(
    const float* __restrict__ x, short* __restrict__ xbp) {
  const int u  = blockIdx.x * 256 + threadIdx.x;
  const int b  = u & (B_NUM - 1);
  const int fp = u >> 11;                          // 0..79: (f, e16-half)
  const int f  = fp >> 1;
  const float* src = x + ((size_t)b * F_NUM + f) * E_DIM + (fp & 1) * 16;
  const float4 v0 = *reinterpret_cast<const float4*>(src);
  const float4 v1 = *reinterpret_cast<const float4*>(src + 4);
  const float4 v2 = *reinterpret_cast<const float4*>(src + 8);
  const float4 v3 = *reinterpret_cast<const float4*>(src + 12);
  const int plane = f * 4 + (fp & 1) * 2;          // e8 plane index
  bf16x8 o0, o1;
  o0[0] = f2bs(v0.x); o0[1] = f2bs(v0.y); o0[2] = f2bs(v0.z); o0[3] = f2bs(v0.w);
  o0[4] = f2bs(v1.x); o0[5] = f2bs(v1.y); o0[6] = f2bs(v1.z); o0[7] = f2bs(v1.w);
  o1[0] = f2bs(v2.x); o1[1] = f2bs(v2.y); o1[2] = f2bs(v2.z); o1[3] = f2bs(v2.w);
  o1[4] = f2bs(v3.x); o1[5] = f2bs(v3.y); o1[6] = f2bs(v3.z); o1[7] = f2bs(v3.w);
  *reinterpret_cast<bf16x8*>(xbp + ((size_t)plane * B_NUM + b) * 8)       = o0;
  *reinterpret_cast<bf16x8*>(xbp + ((size_t)(plane + 1) * B_NUM + b) * 8) = o1;
}

// ---------------------------------------------------------------------------
// Fused dual-MFMA; W-fragments built in-LDS per block; hpart stored as bf16
// (fully-coalesced 512 B/wave epilogue).
//   MFMA1: t[fo,b] = W_p^T xi ; u = bf16(t * xj) is the B-fragment of MFMA2
//   whose A = dw[p,d] replicated over k: MFMA2 does the f-reduction AND the
//   dense fold, accumulating h[d,b] in one f32x4 per n-tile (64 batches/wave).
// grid (8, 65) = 520 blocks, block 256 = 4 waves; LDS 48 KB.
__global__ __launch_bounds__(256, 2) void fused_bilinear_dense_kernel(
    const float* __restrict__ W, const float* __restrict__ dw,
    const short* __restrict__ xbp, unsigned short* __restrict__ hpart) {
  __shared__ unsigned short wraw[PC_SZ * 1024];                  // 24 KB bf16 W [pl][e][f]
  __shared__ __align__(16) unsigned short afrag[PC_SZ * 2 * 512];// 24 KB a-frags
  const int tid  = threadIdx.x;
  const int lane = tid & 63, wv = tid >> 6;
  const int lhi = lane >> 4, llo = lane & 15;
  const int bb = blockIdx.x * 256 + wv * 64;
  const int pc = blockIdx.y;
  const int p0 = pc * PC_SZ;

  // ---- stage this chunk's 12 W matrices (48 KB f32 -> 24 KB bf16 LDS) ----
  {
    const float* Wsrc = W + (size_t)p0 * 1024;
#pragma unroll
    for (int it = 0; it < PC_SZ; ++it) {
      const int L = it * 1024 + tid * 4;
      float4 v = *reinterpret_cast<const float4*>(Wsrc + L);
      u16x4 o;
      o[0] = f2b(v.x); o[1] = f2b(v.y); o[2] = f2b(v.z); o[3] = f2b(v.w);
      *reinterpret_cast<u16x4*>(&wraw[L]) = o;                   // ds_write_b64
    }
  }
  __syncthreads();

  // ---- build per-lane A-fragments with f-PERMUTED m-rows ----
  // A-frag (16x16x32): lane l holds A[m=l&15][k=(l>>4)*8+t]; m -> fo =
  // (m>>2)*8+frag*4+(m&3), so C-row m=lhi*4+r maps to fo=lhi*8+frag*4+r.
#pragma unroll
  for (int s = 0; s < 3; ++s) {
    const int pl = wv * 3 + s;
#pragma unroll
    for (int frag = 0; frag < 2; ++frag) {
      const int fo = (llo >> 2) * 8 + frag * 4 + (llo & 3);
      bf16x8 v;
#pragma unroll
      for (int t = 0; t < 8; ++t)
        v[t] = (short)wraw[pl * 1024 + (lhi * 8 + t) * E_DIM + fo];
      *reinterpret_cast<bf16x8*>(&afrag[(pl * 2 + frag) * 512 + lane * 8]) = v;
    }
  }
  __syncthreads();

  int off[4];                                      // packed-table lane offsets
#pragma unroll
  for (int nt = 0; nt < 4; ++nt)
    off[nt] = (lhi * B_NUM + bb + nt * 16 + llo) * 8;
#define XB8(f, o) (*reinterpret_cast<const bf16x8*>(xbp + (size_t)(f) * 65536 + (o)))

  // pair walk (combinations(range(40),2) order)
  int ii[PC_SZ], jj[PC_SZ];
  {
    int i = 0;
    while ((i + 1) * (79 - (i + 1)) / 2 <= p0) ++i;
    ii[0] = i; jj[0] = i + 1 + (p0 - i * (79 - i) / 2);
  }
#pragma unroll
  for (int k = 1; k < PC_SZ; ++k) {
    int in_ = ii[k - 1], jn = jj[k - 1] + 1;
    if (jn == F_NUM) { ++in_; jn = in_ + 1; }
    ii[k] = in_; jj[k] = jn;
  }

  // xi fragments (reloaded on rare i-change only)
  bf16x8 bf[4];
#pragma unroll
  for (int nt = 0; nt < 4; ++nt) bf[nt] = XB8(ii[0], off[nt]);

  // 2-deep stages for global-memory operands (xj, dw); a-frags come from LDS
  bf16x8 sxj[2][4];
  float sdwf[2];
#pragma unroll
  for (int s = 0; s < 2; ++s) {
#pragma unroll
    for (int nt = 0; nt < 4; ++nt) sxj[s][nt] = XB8(jj[s], off[nt]);
    sdwf[s] = dw[(p0 + s) * D_DIM + llo];
  }

  f32x4 acc[4];
#pragma unroll
  for (int nt = 0; nt < 4; ++nt) acc[nt] = {0.f, 0.f, 0.f, 0.f};
  const f32x4 z = {0.f, 0.f, 0.f, 0.f};

#pragma unroll
  for (int k = 0; k < PC_SZ; ++k) {
    const int s = k & 1;
    const bf16x8 xj0 = sxj[s][0], xj1 = sxj[s][1];
    const bf16x8 xj2 = sxj[s][2], xj3 = sxj[s][3];
    const float dwf = sdwf[s];
    // refill stage s with pair k+2 (lands while k and k+1 compute)
    if (k + 2 < PC_SZ) {
#pragma unroll
      for (int nt = 0; nt < 4; ++nt) sxj[s][nt] = XB8(jj[k + 2], off[nt]);
      sdwf[s] = dw[(p0 + k + 2) * D_DIM + llo];
    }

    // a-frags from LDS (ds_read_b128, compiler-inserted lgkmcnt)
    const bf16x8 a0 = *reinterpret_cast<const bf16x8*>(&afrag[(k * 2 + 0) * 512 + lane * 8]);
    const bf16x8 a1 = *reinterpret_cast<const bf16x8*>(&afrag[(k * 2 + 1) * 512 + lane * 8]);

    // ---- compute pair k: MFMA + u-pack cluster under raised priority ----
    __builtin_amdgcn_s_setprio(1);
    f32x4 c0[4], c1[4];
#pragma unroll
    for (int nt = 0; nt < 4; ++nt) {
      c0[nt] = __builtin_amdgcn_mfma_f32_16x16x32_bf16(a0, bf[nt], z, 0, 0, 0);
      c1[nt] = __builtin_amdgcn_mfma_f32_16x16x32_bf16(a1, bf[nt], z, 0, 0, 0);
    }

    const short dwb = fcvt(dwf);
    bf16x8 a2;
#pragma unroll
    for (int t = 0; t < 8; ++t) a2[t] = dwb;

    const bf16x8 xjl[4] = {xj0, xj1, xj2, xj3};
#pragma unroll
    for (int nt = 0; nt < 4; ++nt) {
      bf16x8 u;                                    // B-frag of MFMA2
#pragma unroll
      for (int t = 0; t < 4; ++t) {
        u[t]     = fcvt(c0[nt][t] * b2f((unsigned short)xjl[nt][t]));
        u[t + 4] = fcvt(c1[nt][t] * b2f((unsigned short)xjl[nt][t + 4]));
      }
      acc[nt] = __builtin_amdgcn_mfma_f32_16x16x32_bf16(a2, u, acc[nt], 0, 0, 0);
    }
    __builtin_amdgcn_s_setprio(0);

    // xi reload on (rare) i-change, wave-uniform branch
    if (k + 1 < PC_SZ && ii[k + 1] != ii[k]) {
#pragma unroll
      for (int nt = 0; nt < 4; ++nt) bf[nt] = XB8(ii[k + 1], off[nt]);
    }
  }
#undef XB8

  // epilogue: acc (lane: b=llo, d=lhi*4+r) -> bf16 hpart[pc][b][d].
  // per nt a wave writes 16 b x 16 d x 2 B = 512 B contiguous (8 B/lane).
  unsigned short* hp = hpart + (size_t)pc * B_NUM * D_DIM;
#pragma unroll
  for (int nt = 0; nt < 4; ++nt) {
    u16x4 o;
    o[0] = f2b(acc[nt][0]); o[1] = f2b(acc[nt][1]);
    o[2] = f2b(acc[nt][2]); o[3] = f2b(acc[nt][3]);
    *reinterpret_cast<u16x4*>(
        hp + (size_t)(bb + nt * 16 + llo) * D_DIM + lhi * 4) = o;
  }
}

// ---------------------------------------------------------------------------
// Final: sum 65 bf16 h-partials + bias, LayerNorm. grid 64, block 256;
// thread = (b, d-pair): reads one uint (2 bf16) per pc -> 1 KB/block/pc
// coalesced; stats via 3-level shfl within the 8-lane d-group.
__global__ __launch_bounds__(256) void reduce_ln_kernel(
    const unsigned short* __restrict__ hpart, const float* __restrict__ bias,
    const float* __restrict__ gamma, const float* __restrict__ beta,
    float* __restrict__ out) {
  const int g  = blockIdx.x * 256 + threadIdx.x;
  const int b  = g >> 3;
  const int d2 = g & 7;                            // d = 2*d2, 2*d2+1
  const uint* hp = reinterpret_cast<const uint*>(hpart) + (size_t)b * 8 + d2;

  float h0 = bias[2 * d2], h1 = bias[2 * d2 + 1];
#pragma unroll 13
  for (int pc = 0; pc < PC_N; ++pc) {
    const uint v = hp[(size_t)pc * B_NUM * 8];
    h0 += b2f((unsigned short)v);
    h1 += b2f((unsigned short)(v >> 16));
  }

  float sum = h0 + h1;
  sum += __shfl_xor(sum, 1); sum += __shfl_xor(sum, 2); sum += __shfl_xor(sum, 4);
  const float mu = sum * (1.f / D_DIM);
  const float dv0 = h0 - mu, dv1 = h1 - mu;
  float v = dv0 * dv0 + dv1 * dv1;
  v += __shfl_xor(v, 1); v += __shfl_xor(v, 2); v += __shfl_xor(v, 4);
  const float rs = rsqrtf(v * (1.f / D_DIM) + LN_EPS);

  float2 o;
  o.x = dv0 * rs * gamma[2 * d2]     + beta[2 * d2];
  o.y = dv1 * rs * gamma[2 * d2 + 1] + beta[2 * d2 + 1];
  *reinterpret_cast<float2*>(out + (size_t)b * D_DIM + 2 * d2) = o;
}

extern "C" void kernel_launch(void* const* d_in, const int* in_sizes, int n_in,
                              void* d_out, int out_size, void* d_ws, size_t ws_size,
                              hipStream_t stream) {
  const float* x     = (const float*)d_in[0];
  const float* W     = (const float*)d_in[1];
  const float* dw    = (const float*)d_in[2];
  const float* db    = (const float*)d_in[3];
  const float* gamma = (const float*)d_in[4];
  const float* beta  = (const float*)d_in[5];
  float* out = (float*)d_out;

  short*          xbp   = (short*)((char*)d_ws + XB_OFF);
  unsigned short* hpart = (unsigned short*)((char*)d_ws + HP_OFF);

  xpack_kernel<<<640, 256, 0, stream>>>(x, xbp);

  dim3 gA(B_NUM / 256, PC_N);
  fused_bilinear_dense_kernel<<<gA, 256, 0, stream>>>(W, dw, xbp, hpart);

  reduce_ln_kernel<<<B_NUM * 8 / 256, 256, 0, stream>>>(hpart, db, gamma, beta, out);
}